// Round 9
// baseline (178.873 us; speedup 1.0000x reference)
//
#include <hip/hip_runtime.h>
#include <hip/hip_bf16.h>
#include <math.h>

#define H 8
#define DM 512
#define DK 64
#define MID 32
#define LL 100
#define EPS 1e-5f
#define NEGV -1000000000.0f

typedef unsigned short u16;
typedef __attribute__((ext_vector_type(8))) short short8b;   // 8 x bf16
typedef __attribute__((ext_vector_type(16))) float f32x16;   // 32x32 MFMA acc

#define MFMA32 __builtin_amdgcn_mfma_f32_32x32x16_bf16

__device__ __forceinline__ unsigned pkbf2(float a, float b) {
    union { __hip_bfloat162 h; unsigned u; } cv;
    cv.h = __float22bfloat162_rn(make_float2(a, b));
    return cv.u;
}
__device__ __forceinline__ u16 bfbits(float a) {
    union { __hip_bfloat16 b; u16 u; } cv;
    cv.b = __float2bfloat16(a);
    return cv.u;
}
__device__ __forceinline__ float bf2f(u16 u) {
    union { u16 u; __hip_bfloat16 b; } cv; cv.u = u;
    return __bfloat162float(cv.b);
}

// ---------------- Kernel 0: split f32 -> bf16 hi/lo, PACKED in MFMA fragment order ----------------
// dst[off*8+j] with off = (tile<<11)|(kb<<6)|(hf<<5)|rr = src[(tile*32+rr)*512 + kb*16 + hf*8 + j]
// Grid (400, 7): y = array id {q,k,v,w1,wk,w2,wv}; W arrays use only x<128.
__global__ __launch_bounds__(256) void cvt_kernel(
    const float* __restrict__ q, const float* __restrict__ k, const float* __restrict__ v,
    const float* __restrict__ w1, const float* __restrict__ wk,
    const float* __restrict__ w2, const float* __restrict__ wv,
    u16* __restrict__ qh, u16* __restrict__ qlo, u16* __restrict__ kh, u16* __restrict__ klo,
    u16* __restrict__ vh, u16* __restrict__ vlo,
    u16* __restrict__ w1h, u16* __restrict__ w1l, u16* __restrict__ wkh, u16* __restrict__ wkl,
    u16* __restrict__ w2h, u16* __restrict__ w2l, u16* __restrict__ wvh, u16* __restrict__ wvl)
{
    const int a = blockIdx.y;
    if (a >= 3 && blockIdx.x >= 128) return;
    const float* src; u16 *dh, *dl;
    switch (a) {
        case 0: src = q;  dh = qh;  dl = qlo; break;
        case 1: src = k;  dh = kh;  dl = klo; break;
        case 2: src = v;  dh = vh;  dl = vlo; break;
        case 3: src = w1; dh = w1h; dl = w1l; break;
        case 4: src = wk; dh = wkh; dl = wkl; break;
        case 5: src = w2; dh = w2h; dl = w2l; break;
        default: src = wv; dh = wvh; dl = wvl; break;
    }
    const int off = blockIdx.x * 256 + threadIdx.x;
    const int rr = off & 31, hf = (off >> 5) & 1, kb = (off >> 6) & 31, tile = off >> 11;
    const float* sp = src + ((size_t)(tile * 32 + rr)) * 512 + kb * 16 + hf * 8;
    float4 x0 = *(const float4*)sp;
    float4 x1 = *(const float4*)(sp + 4);
    float xs[8] = {x0.x, x0.y, x0.z, x0.w, x1.x, x1.y, x1.z, x1.w};
    u16 hb[8], lb[8];
    #pragma unroll
    for (int j = 0; j < 8; ++j) {
        hb[j] = bfbits(xs[j]);
        lb[j] = bfbits(xs[j] - bf2f(hb[j]));
    }
    ushort4 h0; h0.x = hb[0]; h0.y = hb[1]; h0.z = hb[2]; h0.w = hb[3];
    ushort4 h1; h1.x = hb[4]; h1.y = hb[5]; h1.z = hb[6]; h1.w = hb[7];
    ushort4 l0; l0.x = lb[0]; l0.y = lb[1]; l0.z = lb[2]; l0.w = lb[3];
    ushort4 l1; l1.x = lb[4]; l1.y = lb[5]; l1.z = lb[6]; l1.w = lb[7];
    *(ushort4*)(dh + (size_t)off * 8)     = h0;
    *(ushort4*)(dh + (size_t)off * 8 + 4) = h1;
    *(ushort4*)(dl + (size_t)off * 8)     = l0;
    *(ushort4*)(dl + (size_t)off * 8 + 4) = l1;
}

// ---------------- Kernel 1: MFMA proj, zero-LDS, DEPTH-4 pipelined, XCD-grouped ----------------
// 1-D grid of 800, block 128 = 2 waves; decode keeps one W panel per XCD (bid&7).
// Named register sets S0..S3 (no runtime indexing -> no scratch); COMP(Si) then LOAD(Si,kb+4):
// issue->consume distance = 3 compute phases (~150cy) vs depth-1's ~50cy.
#define LDF(p_, kb_) (*(const short8b*)((p_) + (kb_) * 512))
#define DECL_SET(i) short8b Ah##i, Al##i, B0h##i, B0l##i, B1h##i, B1l##i;
#define LOAD_SET(i, kb_) { const int kk = (kb_) & 31; \
    Ah##i = LDF(pAh, kk); Al##i = LDF(pAl, kk); \
    B0h##i = LDF(pB0h, kk); B0l##i = LDF(pB0l, kk); \
    B1h##i = LDF(pB1h, kk); B1l##i = LDF(pB1l, kk); }
#define COMP_SET(i) { \
    acc0 = MFMA32(Ah##i, B0h##i, acc0, 0, 0, 0); \
    acc1 = MFMA32(Ah##i, B1h##i, acc1, 0, 0, 0); \
    acc0 = MFMA32(Ah##i, B0l##i, acc0, 0, 0, 0); \
    acc1 = MFMA32(Ah##i, B1l##i, acc1, 0, 0, 0); \
    acc0 = MFMA32(Al##i, B0h##i, acc0, 0, 0, 0); \
    acc1 = MFMA32(Al##i, B1h##i, acc1, 0, 0, 0); }
__global__ __launch_bounds__(128) void proj_kernel(
    const u16* __restrict__ qh, const u16* __restrict__ qlo,
    const u16* __restrict__ kh, const u16* __restrict__ klo,
    const u16* __restrict__ vh, const u16* __restrict__ vlo,
    const u16* __restrict__ w1h, const u16* __restrict__ w1l,
    const u16* __restrict__ wkh, const u16* __restrict__ wkl,
    const u16* __restrict__ w2h, const u16* __restrict__ w2l,
    const u16* __restrict__ wvh, const u16* __restrict__ wvl,
    const float* __restrict__ bq1, const float* __restrict__ gw1, const float* __restrict__ gb1,
    const float* __restrict__ bk , const float* __restrict__ gwk, const float* __restrict__ gbk,
    const float* __restrict__ bq2, const float* __restrict__ gw2, const float* __restrict__ gb2,
    const float* __restrict__ bv , const float* __restrict__ gwv, const float* __restrict__ gbv,
    float* __restrict__ q1o, u16* __restrict__ kbf,
    float* __restrict__ q2o, u16* __restrict__ vtbf)
{
    const int bid = blockIdx.x;
    const int x = bid & 7, j = bid >> 3;
    const int rt = j % 50;
    const int pair = x * 2 + j / 50;    // 0..15
    const int p = pair >> 2, ct = pair & 3;

    const int t = threadIdx.x, wc = t >> 6, lane = t & 63, ql = lane & 31, hf = lane >> 5;

    const u16 *Xhg, *Xlg, *Whg, *Wlg; const float *bias, *gw, *gb;
    if (p == 0)      { Xhg=qh; Xlg=qlo; Whg=w1h; Wlg=w1l; bias=bq1; gw=gw1; gb=gb1; }
    else if (p == 1) { Xhg=kh; Xlg=klo; Whg=wkh; Wlg=wkl; bias=bk;  gw=gwk; gb=gbk; }
    else if (p == 2) { Xhg=qh; Xlg=qlo; Whg=w2h; Wlg=w2l; bias=bq2; gw=gw2; gb=gb2; }
    else             { Xhg=vh; Xlg=vlo; Whg=wvh; Wlg=wvl; bias=bv;  gw=gwv; gb=gbv; }

    const int ctile = ct * 4 + wc * 2;
    const u16* pAh  = Xhg + (size_t)rt * 16384 + hf * 256 + ql * 8;
    const u16* pAl  = Xlg + (size_t)rt * 16384 + hf * 256 + ql * 8;
    const u16* pB0h = Whg + (size_t)ctile * 16384 + hf * 256 + ql * 8;
    const u16* pB0l = Wlg + (size_t)ctile * 16384 + hf * 256 + ql * 8;
    const u16* pB1h = pB0h + 16384;
    const u16* pB1l = pB0l + 16384;

    f32x16 acc0 = {0.f,0.f,0.f,0.f,0.f,0.f,0.f,0.f,0.f,0.f,0.f,0.f,0.f,0.f,0.f,0.f};
    f32x16 acc1 = {0.f,0.f,0.f,0.f,0.f,0.f,0.f,0.f,0.f,0.f,0.f,0.f,0.f,0.f,0.f,0.f};

    DECL_SET(0) DECL_SET(1) DECL_SET(2) DECL_SET(3)
    LOAD_SET(0, 0) LOAD_SET(1, 1) LOAD_SET(2, 2) LOAD_SET(3, 3)

    for (int kb = 0; kb < 32; kb += 4) {
        COMP_SET(0) LOAD_SET(0, kb + 4)
        COMP_SET(1) LOAD_SET(1, kb + 5)
        COMP_SET(2) LOAD_SET(2, kb + 6)
        COMP_SET(3) LOAD_SET(3, kb + 7)
    }

    // bias + CELU + GroupNorm (the wave's 64 cols ARE the group; stats via in-half butterfly)
    const int c0 = ct * 128 + wc * 64 + ql;
    const int c1 = c0 + 32;
    const float b0 = bias[c0], b1 = bias[c1];
    const float gw0 = gw[c0], gb0 = gb[c0], gw1_ = gw[c1], gb1_ = gb[c1];
    float y0[16], y1[16], s[16], sq[16];
    #pragma unroll
    for (int r = 0; r < 16; ++r) {
        float a0 = acc0[r] + b0;
        float a1 = acc1[r] + b1;
        a0 = a0 > 0.f ? a0 : expm1f(a0);
        a1 = a1 > 0.f ? a1 : expm1f(a1);
        y0[r] = a0; y1[r] = a1;
        s[r] = a0 + a1; sq[r] = a0 * a0 + a1 * a1;
    }
    #pragma unroll
    for (int off = 1; off < 32; off <<= 1) {
        #pragma unroll
        for (int r = 0; r < 16; ++r) {
            s[r]  += __shfl_xor(s[r],  off, 64);
            sq[r] += __shfl_xor(sq[r], off, 64);
        }
    }
    const int hh = ct * 2 + wc;
    #pragma unroll
    for (int r = 0; r < 16; ++r) {
        const float mu  = s[r] * (1.f / 64.f);
        const float var = sq[r] * (1.f / 64.f) - mu * mu;
        const float inv = rsqrtf(var + EPS);
        const float yn0 = (y0[r] - mu) * inv * gw0 + gb0;
        const float yn1 = (y1[r] - mu) * inv * gw1_ + gb1_;
        const int row = (r & 3) + 8 * (r >> 2) + 4 * hf;
        const int rg = rt * 32 + row;
        const int b = rg / 100;
        const int l = rg - b * 100;
        const size_t bh = (size_t)(b * H + hh);
        if (p == 0) {
            q1o[(bh * 100 + l) * 64 + ql]      = yn0;
            q1o[(bh * 100 + l) * 64 + 32 + ql] = yn1;
        } else if (p == 2) {
            q2o[(bh * 100 + l) * 64 + ql]      = yn0;
            q2o[(bh * 100 + l) * 64 + 32 + ql] = yn1;
        } else if (p == 1) {
            kbf[(bh * 128 + l) * 64 + ql]      = bfbits(yn0);
            kbf[(bh * 128 + l) * 64 + 32 + ql] = bfbits(yn1);
        } else {
            vtbf[(bh * 64 + ql) * 128 + l]      = bfbits(yn0);
            vtbf[(bh * 64 + 32 + ql) * 128 + l] = bfbits(yn1);
        }
    }
}

// ---------------- Kernel 2: MFMA attention, 4 waves (w_k x w_m) ---------------- (unchanged)
__global__ __launch_bounds__(256, 2) void attn_kernel(
    const float* __restrict__ q1o, const u16* __restrict__ kbf,
    const float* __restrict__ q2o, const u16* __restrict__ vtbf,
    const float* __restrict__ mask,
    const float* __restrict__ We, const float* __restrict__ be,
    const float* __restrict__ Wsv, const float* __restrict__ bs,
    const float* __restrict__ Wsq, const float* __restrict__ bsq,
    float* __restrict__ out)
{
    __shared__ float lds_We[32 * 64];       // 8 KB
    __shared__ float lds_score[128 * 33];   // 16.9 KB
    __shared__ float lds_pool[2][32 * 33];  // 8.4 KB  [wk]
    __shared__ float lds_of[2][16 * 64];    // 8 KB    [wm][r][lane]
    __shared__ float lds_mx[2][32], lds_se[2][32], lds_ms[2][32];

    const int bh = blockIdx.x, b = bh >> 3, h = bh & 7, qt = blockIdx.y;
    const int tid = threadIdx.x;
    const int w = tid >> 6, lane = tid & 63;
    const int wk = w >> 1, wm = w & 1;
    const int ql = lane & 31, hf = lane >> 5;
    const int q0 = qt * 32, q = q0 + ql;
    const int qc = q < 100 ? q : 99;

    for (int i = tid * 4; i < 2048; i += 1024)
        *(float4*)(lds_We + i) = *(const float4*)(We + i);
    for (int i = tid; i < 2 * 32 * 33; i += 256)
        ((float*)lds_pool)[i] = 0.f;

    const u16* kb = kbf + (size_t)bh * 128 * 64;
    short8b A[2][4];
    #pragma unroll
    for (int mtl = 0; mtl < 2; ++mtl)
        #pragma unroll
        for (int ks = 0; ks < 4; ++ks)
            A[mtl][ks] = *(const short8b*)(kb + (size_t)((2 * wk + mtl) * 32 + ql) * 64 + ks * 16 + hf * 8);

    float q1r[4][8];
    const float* q1p = q1o + ((size_t)bh * 100 + qc) * 64;
    #pragma unroll
    for (int ks = 0; ks < 4; ++ks) {
        float4 u0 = *(const float4*)(q1p + ks * 16 + hf * 8);
        float4 u1 = *(const float4*)(q1p + ks * 16 + hf * 8 + 4);
        q1r[ks][0] = u0.x; q1r[ks][1] = u0.y; q1r[ks][2] = u0.z; q1r[ks][3] = u0.w;
        q1r[ks][4] = u1.x; q1r[ks][5] = u1.y; q1r[ks][6] = u1.z; q1r[ks][7] = u1.w;
    }
    const float bsv = bs[0];

    float sc[2][16];
    #pragma unroll
    for (int mtl = 0; mtl < 2; ++mtl)
        #pragma unroll
        for (int r = 0; r < 16; ++r) sc[mtl][r] = 0.f;

    __syncthreads();

    for (int mi = 0; mi < 16; ++mi) {
        const int m = wm * 16 + mi;
        const float bem = be[m], wsm = Wsv[m];
        short8b Bf[4];
        #pragma unroll
        for (int ks = 0; ks < 4; ++ks) {
            const float* wp_ = lds_We + m * 64 + ks * 16 + hf * 8;
            float4 w0 = *(const float4*)(wp_);
            float4 w1 = *(const float4*)(wp_ + 4);
            union { unsigned u[4]; short8b v; } pk;
            pk.u[0] = pkbf2(w0.x * q1r[ks][0], w0.y * q1r[ks][1]);
            pk.u[1] = pkbf2(w0.z * q1r[ks][2], w0.w * q1r[ks][3]);
            pk.u[2] = pkbf2(w1.x * q1r[ks][4], w1.y * q1r[ks][5]);
            pk.u[3] = pkbf2(w1.z * q1r[ks][6], w1.w * q1r[ks][7]);
            Bf[ks] = pk.v;
        }
        #pragma unroll
        for (int mtl = 0; mtl < 2; ++mtl) {
            const int mt = 2 * wk + mtl;
            f32x16 c = {0.f,0.f,0.f,0.f,0.f,0.f,0.f,0.f,0.f,0.f,0.f,0.f,0.f,0.f,0.f,0.f};
            c = MFMA32(A[mtl][0], Bf[0], c, 0, 0, 0);
            c = MFMA32(A[mtl][1], Bf[1], c, 0, 0, 0);
            c = MFMA32(A[mtl][2], Bf[2], c, 0, 0, 0);
            c = MFMA32(A[mtl][3], Bf[3], c, 0, 0, 0);
            float psum = 0.f, psum4 = 0.f;
            #pragma unroll
            for (int r = 0; r < 16; ++r) {
                float tv = fmaxf(c[r] + bem, 0.f);
                sc[mtl][r] = fmaf(tv, wsm, sc[mtl][r]);
                if (mt != 3) psum += tv;
                else if (r < 4) psum4 += tv;
            }
            if (mt == 3) psum = (hf == 0) ? psum4 : 0.f;
            psum += __shfl_xor(psum, 32, 64);
            if (hf == 0) lds_pool[wk][ql * 33 + m] += psum;
        }
    }

    float msum = 0.f;
    const float* mrow = mask + ((size_t)b * 100 + qc) * 100;
    #pragma unroll
    for (int mtl = 0; mtl < 2; ++mtl) {
        const int mt = 2 * wk + mtl;
        #pragma unroll
        for (int g = 0; g < 4; ++g) {
            int k0 = mt * 32 + g * 8 + hf * 4;
            if (k0 < 100) {
                float4 mk = *(const float4*)(mrow + k0);
                msum += mk.x + mk.y + mk.z + mk.w;
                if (mk.x == 0.f) sc[mtl][g * 4 + 0] = NEGV;
                if (mk.y == 0.f) sc[mtl][g * 4 + 1] = NEGV;
                if (mk.z == 0.f) sc[mtl][g * 4 + 2] = NEGV;
                if (mk.w == 0.f) sc[mtl][g * 4 + 3] = NEGV;
            } else {
                sc[mtl][g * 4 + 0] = -INFINITY; sc[mtl][g * 4 + 1] = -INFINITY;
                sc[mtl][g * 4 + 2] = -INFINITY; sc[mtl][g * 4 + 3] = -INFINITY;
            }
        }
    }
    msum += __shfl_xor(msum, 32, 64);

    if (wm == 0) {
        #pragma unroll
        for (int mtl = 0; mtl < 2; ++mtl)
            #pragma unroll
            for (int r = 0; r < 16; ++r) {
                int row = (2 * wk + mtl) * 32 + (r & 3) + 8 * (r >> 2) + 4 * hf;
                lds_score[row * 33 + ql] = sc[mtl][r];
            }
    }
    __syncthreads();
    if (wm == 1) {
        #pragma unroll
        for (int mtl = 0; mtl < 2; ++mtl)
            #pragma unroll
            for (int r = 0; r < 16; ++r) {
                int row = (2 * wk + mtl) * 32 + (r & 3) + 8 * (r >> 2) + 4 * hf;
                lds_score[row * 33 + ql] += sc[mtl][r];
            }
    }
    __syncthreads();

    float mx = -INFINITY;
    #pragma unroll
    for (int mtl = 0; mtl < 2; ++mtl)
        #pragma unroll
        for (int r = 0; r < 16; ++r) {
            int row = (2 * wk + mtl) * 32 + (r & 3) + 8 * (r >> 2) + 4 * hf;
            float sv = lds_score[row * 33 + ql] + bsv;
            sc[mtl][r] = sv;
            mx = fmaxf(mx, sv);
        }
    mx = fmaxf(mx, __shfl_xor(mx, 32, 64));
    if (hf == 0 && wm == 0) { lds_mx[wk][ql] = mx; lds_ms[wk][ql] = msum; }
    __syncthreads();
    mx = fmaxf(lds_mx[0][ql], lds_mx[1][ql]);
    const float msumT = lds_ms[0][ql] + lds_ms[1][ql];
    float se = 0.f;
    #pragma unroll
    for (int mtl = 0; mtl < 2; ++mtl)
        #pragma unroll
        for (int r = 0; r < 16; ++r) {
            float ev = expf(sc[mtl][r] - mx);
            sc[mtl][r] = ev;
            se += ev;
        }
    se += __shfl_xor(se, 32, 64);
    if (hf == 0 && wm == 0) lds_se[wk][ql] = se;
    __syncthreads();
    const float inv_se = 1.f / (lds_se[0][ql] + lds_se[1][ql]);
    #pragma unroll
    for (int mtl = 0; mtl < 2; ++mtl)
        #pragma unroll
        for (int r = 0; r < 16; ++r) sc[mtl][r] *= inv_se;

    const int nks = 4 - wk;
    short8b A2[4];
    #pragma unroll
    for (int ksl = 0; ksl < 4; ++ksl) {
        if (ksl < nks) {
            const int s_ = ksl & 1, mtl = ksl >> 1;
            unsigned a0 = pkbf2(sc[mtl][8 * s_ + 0], sc[mtl][8 * s_ + 1]);
            unsigned a1 = pkbf2(sc[mtl][8 * s_ + 2], sc[mtl][8 * s_ + 3]);
            unsigned b0 = pkbf2(sc[mtl][8 * s_ + 4], sc[mtl][8 * s_ + 5]);
            unsigned b1 = pkbf2(sc[mtl][8 * s_ + 6], sc[mtl][8 * s_ + 7]);
            unsigned o0 = hf ? b0 : a0, o1 = hf ? b1 : a1;
            unsigned s0 = hf ? a0 : b0, s1 = hf ? a1 : b1;
            unsigned r0_ = (unsigned)__shfl_xor((int)s0, 32, 64);
            unsigned r1_ = (unsigned)__shfl_xor((int)s1, 32, 64);
            union { unsigned u[4]; short8b v; } pk;
            pk.u[0] = hf ? r0_ : o0;  pk.u[1] = hf ? r1_ : o1;
            pk.u[2] = hf ? o0 : r0_;  pk.u[3] = hf ? o1 : r1_;
            A2[ksl] = pk.v;
        }
    }

    const u16* vb = vtbf + (size_t)bh * 64 * 128 + (size_t)(wm * 32 + ql) * 128;
    f32x16 o = {0.f,0.f,0.f,0.f,0.f,0.f,0.f,0.f,0.f,0.f,0.f,0.f,0.f,0.f,0.f,0.f};
    #pragma unroll
    for (int ksl = 0; ksl < 4; ++ksl) {
        if (ksl < nks) {
            short8b vf = *(const short8b*)(vb + (4 * wk + ksl) * 16 + hf * 8);
            o = MFMA32(A2[ksl], vf, o, 0, 0, 0);
        }
    }

    if (wk == 0) {
        #pragma unroll
        for (int r = 0; r < 16; ++r) lds_of[wm][r * 64 + lane] = o[r];
    }
    __syncthreads();
    if (wk == 1) {
        #pragma unroll
        for (int r = 0; r < 16; ++r) o[r] += lds_of[wm][r * 64 + lane];

        const float invm = 1.f / msumT;
        short8b A3[2], B3[2];
        #pragma unroll
        for (int ks = 0; ks < 2; ++ks) {
            const float* p0_ = lds_pool[0] + ql * 33 + ks * 16 + hf * 8;
            const float* p1_ = lds_pool[1] + ql * 33 + ks * 16 + hf * 8;
            union { unsigned u[4]; short8b v; } pk;
            pk.u[0] = pkbf2((p0_[0]+p1_[0])*invm, (p0_[1]+p1_[1])*invm);
            pk.u[1] = pkbf2((p0_[2]+p1_[2])*invm, (p0_[3]+p1_[3])*invm);
            pk.u[2] = pkbf2((p0_[4]+p1_[4])*invm, (p0_[5]+p1_[5])*invm);
            pk.u[3] = pkbf2((p0_[6]+p1_[6])*invm, (p0_[7]+p1_[7])*invm);
            A3[ks] = pk.v;
            const float* wqp = Wsq + (size_t)(wm * 32 + ql) * 32 + ks * 16 + hf * 8;
            float4 c0 = *(const float4*)(wqp);
            float4 c1 = *(const float4*)(wqp + 4);
            union { unsigned u[4]; short8b v; } pk2;
            pk2.u[0] = pkbf2(c0.x, c0.y); pk2.u[1] = pkbf2(c0.z, c0.w);
            pk2.u[2] = pkbf2(c1.x, c1.y); pk2.u[3] = pkbf2(c1.z, c1.w);
            B3[ks] = pk2.v;
        }
        f32x16 z = {0.f,0.f,0.f,0.f,0.f,0.f,0.f,0.f,0.f,0.f,0.f,0.f,0.f,0.f,0.f,0.f};
        z = MFMA32(A3[0], B3[0], z, 0, 0, 0);
        z = MFMA32(A3[1], B3[1], z, 0, 0, 0);

        const float bsqv = bsq[wm * 32 + ql];
        const float* q2p = q2o + (size_t)bh * 100 * 64;
        const int dcol = wm * 32 + ql;
        #pragma unroll
        for (int r = 0; r < 16; ++r) {
            int qr = q0 + (r & 3) + 8 * (r >> 2) + 4 * hf;
            if (qr < 100) {
                float chv = 1.f / (1.f + expf(-(z[r] + bsqv)));
                float ov  = o[r] * chv * q2p[(size_t)qr * 64 + dcol];
                out[((size_t)(b * 100 + qr)) * DM + h * 64 + dcol] = ov;
            }
        }
    }
}

extern "C" void kernel_launch(void* const* d_in, const int* in_sizes, int n_in,
                              void* d_out, int out_size, void* d_ws, size_t ws_size,
                              hipStream_t stream)
{
    const float* query = (const float*)d_in[0];
    const float* key   = (const float*)d_in[1];
    const float* value = (const float*)d_in[2];
    const float* mask  = (const float*)d_in[3];
    const float* Wq1 = (const float*)d_in[4];
    const float* bq1 = (const float*)d_in[5];
    const float* gw1 = (const float*)d_in[6];
    const float* gb1 = (const float*)d_in[7];
    const float* Wk  = (const float*)d_in[8];
    const float* bk  = (const float*)d_in[9];
    const float* gwk = (const float*)d_in[10];
    const float* gbk = (const float*)d_in[11];
    const float* Wq2 = (const float*)d_in[12];
    const float* bq2 = (const float*)d_in[13];
    const float* gw2 = (const float*)d_in[14];
    const float* gb2 = (const float*)d_in[15];
    const float* Wv  = (const float*)d_in[16];
    const float* bv  = (const float*)d_in[17];
    const float* gwv = (const float*)d_in[18];
    const float* gbv = (const float*)d_in[19];
    const float* We  = (const float*)d_in[20];
    const float* be  = (const float*)d_in[21];
    const float* Ws  = (const float*)d_in[22];
    const float* bs  = (const float*)d_in[23];
    const float* Wsq = (const float*)d_in[24];
    const float* bsq = (const float*)d_in[25];

    float* wsf = (float*)d_ws;
    float* q1o = wsf;                                   // 819200 f32
    float* q2o = wsf + 819200;                          // 819200 f32
    u16* kbf   = (u16*)(wsf + 1638400);                 // 128*128*64
    u16* vtbf  = kbf + 1048576;                         // 128*64*128
    u16* c0    = vtbf + 1048576;
    u16 *qh = c0, *qlo = qh + 819200, *khh = qlo + 819200, *klo = khh + 819200,
        *vhh = klo + 819200, *vlo = vhh + 819200;
    u16* wbase = vlo + 819200;
    u16 *w1h = wbase,          *w1l = w1h + 262144,
        *wkh = w1l + 262144,   *wkl = wkh + 262144,
        *w2h = wkl + 262144,   *w2l = w2h + 262144,
        *wvh = w2l + 262144,   *wvl = wvh + 262144;

    dim3 gc(400, 7);
    cvt_kernel<<<gc, 256, 0, stream>>>(query, key, value, Wq1, Wk, Wq2, Wv,
        qh, qlo, khh, klo, vhh, vlo, w1h, w1l, wkh, wkl, w2h, w2l, wvh, wvl);

    proj_kernel<<<800, 128, 0, stream>>>(
        qh, qlo, khh, klo, vhh, vlo, w1h, w1l, wkh, wkl, w2h, w2l, wvh, wvl,
        bq1, gw1, gb1, bk, gwk, gbk, bq2, gw2, gb2, bv, gwv, gbv,
        q1o, kbf, q2o, vtbf);

    dim3 g2(128, 4);
    attn_kernel<<<g2, 256, 0, stream>>>(q1o, kbf, q2o, vtbf, mask,
        We, be, Ws, bs, Wsq, bsq, (float*)d_out);
}